// Round 7
// baseline (452.575 us; speedup 1.0000x reference)
//
#include <hip/hip_runtime.h>
#include <stdint.h>

typedef __bf16 bf16;
typedef __bf16 bf16x8 __attribute__((ext_vector_type(8)));
typedef float f32x4 __attribute__((ext_vector_type(4)));

__device__ __forceinline__ void gload_lds16(const void* g, void* l) {
    __builtin_amdgcn_global_load_lds(
        (const __attribute__((address_space(1))) unsigned int*)g,
        (__attribute__((address_space(3))) unsigned int*)l, 16, 0, 0);
}

#define BAR()    asm volatile("s_barrier" ::: "memory")
#define WAITV(N) asm volatile("s_waitcnt vmcnt(" #N ")" ::: "memory")

// ============================================================================
// 256x256-tile 8-phase GEMM, PANELIZED operands.
// All staged arrays live in ws as [z][panel = k/32][rows][32 k] so each 16-KB
// LDS region (256 rows x 32 k) is CONTIGUOUS in global memory -> staging is
// pure streaming (1 KB/wave bursts) instead of 64-B chunks at 2-KB stride.
// Schedule/vmcnt/swizzle identical to the proven round-6 kernel.
// OMODE: 0 = bf16 panelized out (cLog/cBatch/cPanel route the write);
//        1 = bf16 transposed-panelized out (VT[z][lk/32][1024 e][32 lk]);
//        2 = f32 row-major out (final Y).
// ============================================================================
template<int OMODE>
__global__ __launch_bounds__(512, 2)
void gemm256(const bf16* __restrict__ A, const bf16* __restrict__ B,
             void* __restrict__ Cv, int K, int N,
             long batchA, long batchB, long batchC,
             long aPanel, long bPanel, long cPanel, long cBatch, int cLog,
             float alpha, int nbx, int nby, int GC)
{
    __shared__ __align__(16) bf16 lds[2][4][8192];

    // ---- block remap: bijective XCD swizzle (m204) + stripe order ----
    const int nwg  = gridDim.x;
    const int orig = blockIdx.x;
    const int q8   = nwg >> 3, r8 = nwg & 7;
    const int xcd  = orig & 7, lid = orig >> 3;
    const int p    = (xcd < r8 ? xcd * (q8 + 1) : r8 * (q8 + 1) + (xcd - r8) * q8) + lid;
    const int perb = nbx * nby;
    const int z    = p / perb;
    const int pb   = p - z * perb;
    const int sw   = nby * GC;
    const int st   = pb / sw;
    const int rem  = pb - st * sw;
    const int by   = rem / GC;
    const int bx   = st * GC + (rem - by * GC);

    const long rowb = (long)by << 8;
    const long colb = (long)bx << 8;

    const int t  = threadIdx.x;
    const int l  = t & 63;
    const int w  = t >> 6;
    const int wm = w >> 2;          // 0..1
    const int wn = w & 3;           // 0..3

    // ---- staging: regions are contiguous 16-KB blocks; pre-swizzled source ----
    const int sLb = (t * 16) ^ (((t >> 3) & 3) << 4);   // byte offset in 8-KB half
    const char* gAc = (const char*)A + 2L * ((long)z * batchA + rowb * 32);
    const char* gBc = (const char*)B + 2L * ((long)z * batchB + colb * 32);
    const long kA = 2L * aPanel;    // bytes per k-panel step (A)
    const long kB = 2L * bPanel;    // bytes per k-panel step (B)
    const int  d0 = t * 8, d1 = t * 8 + 4096;           // LDS elem offsets

    // ---- ds_read byte offsets within a 16KB region (swizzled) ----
    const int xl    = ((l >> 1) & 3) << 4;
    const int aBase = ((wm * 128 + (l & 15)) * 64 + ((l >> 4) << 4)) ^ xl;
    const int bBase = ((wn * 64  + (l & 15)) * 64 + ((l >> 4) << 4)) ^ xl;

    f32x4 acc[8][4] = {};
    bf16x8 av[4], bv[4];

#define STG(S, R, G, KS, P) do { \
    const char* _g = (G) + (long)(P) * (KS); \
    gload_lds16(_g + sLb,        &lds[S][R][d0]); \
    gload_lds16(_g + sLb + 8192, &lds[S][R][d1]); \
  } while (0)

#define RD(S, R, OFF) (*(const bf16x8*)((const char*)&lds[S][R][0] + (OFF)))

#define MM(MB) \
    __builtin_amdgcn_s_setprio(1); \
    _Pragma("unroll") for (int mi = 0; mi < 4; ++mi) \
      _Pragma("unroll") for (int nj = 0; nj < 4; ++nj) \
        acc[MB + mi][nj] = __builtin_amdgcn_mfma_f32_16x16x32_bf16(av[mi], bv[nj], acc[MB + mi][nj], 0, 0, 0); \
    __builtin_amdgcn_s_setprio(0);

#define PH1(S, STGX) { \
    _Pragma("unroll") for (int nj = 0; nj < 4; ++nj) bv[nj] = RD(S, 2, bBase + nj * 1024); \
    _Pragma("unroll") for (int mi = 0; mi < 4; ++mi) av[mi] = RD(S, 0, aBase + mi * 1024); \
    STGX; BAR(); MM(0) BAR(); }

#define PH2(S, STGX) { \
    _Pragma("unroll") for (int mi = 0; mi < 4; ++mi) av[mi] = RD(S, 0, aBase + 4096 + mi * 1024); \
    STGX; BAR(); MM(4) BAR(); }

#define PH3(S, STGX) { \
    _Pragma("unroll") for (int nj = 0; nj < 4; ++nj) bv[nj] = RD(S, 3, bBase + nj * 1024); \
    _Pragma("unroll") for (int mi = 0; mi < 4; ++mi) av[mi] = RD(S, 1, aBase + mi * 1024); \
    STGX; BAR(); MM(0) BAR(); }

#define PH4(S, STGX, WT) { \
    _Pragma("unroll") for (int mi = 0; mi < 4; ++mi) av[mi] = RD(S, 1, aBase + 4096 + mi * 1024); \
    STGX; BAR(); MM(4) WT; BAR(); }

    // prologue (panels 0..3 of each K-tile pair)
    STG(0, 0, gAc, kA, 0);
    STG(0, 1, gAc, kA, 1);
    STG(0, 2, gBc, kB, 0);
    STG(0, 3, gBc, kB, 1);
    STG(1, 2, gBc, kB, 2);
    STG(1, 0, gAc, kA, 2);
    STG(1, 3, gBc, kB, 3);
    WAITV(6);
    BAR();

    const int NI = K >> 7;
    for (int i = 0; i < NI - 1; ++i) {
        const int pp = i << 2;                   // panel base of this iteration
        PH1(0, STG(1, 1, gAc, kA, pp + 3));
        PH2(0, STG(0, 2, gBc, kB, pp + 4));
        PH3(0, STG(0, 0, gAc, kA, pp + 4));
        PH4(0, STG(0, 3, gBc, kB, pp + 5), WAITV(6));
        PH1(1, STG(0, 1, gAc, kA, pp + 5));
        PH2(1, STG(1, 2, gBc, kB, pp + 6));
        PH3(1, STG(1, 0, gAc, kA, pp + 6));
        PH4(1, STG(1, 3, gBc, kB, pp + 7), WAITV(6));
    }
    {
        const int pp = (NI - 1) << 2;
        PH1(0, STG(1, 1, gAc, kA, pp + 3));
        PH2(0, );
        PH3(0, );
        PH4(0, , WAITV(0));
        PH1(1, );
        PH2(1, );
        PH3(1, );
        PH4(1, , );
    }
#undef STG
#undef RD
#undef MM
#undef PH1
#undef PH2
#undef PH3
#undef PH4

    // ---- epilogue. C/D frag layout: col=lane&15, row=(lane>>4)*4+reg [m89] ----
    const int r0 = (l >> 4) << 2;
    const long rbase = rowb + wm * 128 + r0;
    const long cb0   = colb + wn * 64 + (l & 15);

    if constexpr (OMODE == 2) {
        // f32 row-major (final Y), batched
#pragma unroll
        for (int mf = 0; mf < 8; ++mf)
#pragma unroll
          for (int nj = 0; nj < 4; ++nj) {
            const long col = cb0 + nj * 16;
#pragma unroll
            for (int r = 0; r < 4; ++r)
                ((float*)Cv)[(long)z * batchC + (rbase + mf * 16 + r) * (long)N + col]
                    = acc[mf][nj][r] * alpha;
          }
    } else if constexpr (OMODE == 1) {
        // VT[z][lk/32][1024 e][32 lk]; 4 consecutive lk (r=0..3) -> 8B store
#pragma unroll
        for (int mf = 0; mf < 8; ++mf)
#pragma unroll
          for (int nj = 0; nj < 4; ++nj) {
            const long grow = rbase + mf * 16;      // lk
            const long e    = cb0 + nj * 16;        // embedding dim
            const long zz   = grow >> 12;
            const long lkz  = grow & 4095;
            union { bf16 h[4]; uint2 u; } pk;
#pragma unroll
            for (int r = 0; r < 4; ++r) pk.h[r] = (bf16)(acc[mf][nj][r] * alpha);
            *(uint2*)&((bf16*)Cv)[zz * 4194304L + (lkz >> 5) * 32768L + e * 32 + (lkz & 31)] = pk.u;
          }
    } else {
        // bf16 panelized: idx = z*batchC + (grow>>cLog)*cBatch
        //                 + (gcol>>5)*cPanel + (grow&mask)*32 + (gcol&31)
        const long cMask = (1L << cLog) - 1;
#pragma unroll
        for (int mf = 0; mf < 8; ++mf)
#pragma unroll
          for (int nj = 0; nj < 4; ++nj) {
            const long gcol = cb0 + nj * 16;
            const long cpart = (long)z * batchC + (gcol >> 5) * cPanel + (gcol & 31);
#pragma unroll
            for (int r = 0; r < 4; ++r) {
                const long grow = rbase + mf * 16 + r;
                const long idx = cpart + (grow >> cLog) * cBatch + (grow & cMask) * 32;
                ((bf16*)Cv)[idx] = (bf16)(acc[mf][nj][r] * alpha);
            }
          }
    }
}

// f32 row-major [M][1024] -> bf16 panelized [32][M][32]; one vec8 per thread
__global__ void cvt_pan(const float* __restrict__ in, bf16* __restrict__ out,
                        long M, long n8)
{
    const long stride = (long)gridDim.x * 256;
    for (long v = (long)blockIdx.x * 256 + threadIdx.x; v < n8; v += stride) {
        const float4* pp = (const float4*)in + v * 2;
        float4 a = pp[0], b = pp[1];
        union { bf16 h[8]; uint4 u; } o;
        o.h[0] = (bf16)a.x; o.h[1] = (bf16)a.y; o.h[2] = (bf16)a.z; o.h[3] = (bf16)a.w;
        o.h[4] = (bf16)b.x; o.h[5] = (bf16)b.y; o.h[6] = (bf16)b.z; o.h[7] = (bf16)b.w;
        const long row = v >> 7;        // 128 vec8 per 1024-row
        const int  kv  = (int)(v & 127);
        const long addr = (long)(kv >> 2) * (M * 32) + row * 32 + (kv & 3) * 8;
        *(uint4*)&out[addr] = o.u;
    }
}

// 4 weights (1024x1024 f32 each) -> contiguous panelized bf16 [32][1024][32]
__global__ void cvt_w4(const float* __restrict__ wq, const float* __restrict__ wk,
                       const float* __restrict__ wv, const float* __restrict__ wo,
                       bf16* __restrict__ out)
{
    const long i  = (long)blockIdx.x * 256 + threadIdx.x;
    const int seg = (int)(i >> 17);            // 131072 vec8 per weight
    const long j  = i & 131071;
    const float* src = seg == 0 ? wq : seg == 1 ? wk : seg == 2 ? wv : wo;
    const float4* pp = (const float4*)src + j * 2;
    float4 a = pp[0], b = pp[1];
    union { bf16 h[8]; uint4 u; } o;
    o.h[0] = (bf16)a.x; o.h[1] = (bf16)a.y; o.h[2] = (bf16)a.z; o.h[3] = (bf16)a.w;
    o.h[4] = (bf16)b.x; o.h[5] = (bf16)b.y; o.h[6] = (bf16)b.z; o.h[7] = (bf16)b.w;
    const long row = j >> 7;
    const int  kv  = (int)(j & 127);
    out += (long)seg * 1048576;
    *(uint4*)&out[(long)(kv >> 2) * 32768 + row * 32 + (kv & 3) * 8] = o.u;
}

// softmax on panelized P [z][128][1024][32]; block = 512 thr handles 4 rows.
// thread t: panel = t>>2, row = r0 + (t&3) -> 64-B contiguous per thread,
// 256-B contiguous per 4-thread group.
__global__ __launch_bounds__(512)
void softmax_pan(bf16* __restrict__ P)
{
    const int t  = threadIdx.x;
    const int g  = blockIdx.x;
    const long z = g >> 8;
    const int r0 = (g & 255) << 2;
    bf16* rp = P + z * 4194304L + (long)(t >> 2) * 32768L + (long)(r0 + (t & 3)) * 32;

    union U { uint4 u; bf16 h[8]; };
    U d[4];
#pragma unroll
    for (int i = 0; i < 4; ++i) d[i].u = ((const uint4*)rp)[i];
    float v[32];
#pragma unroll
    for (int i = 0; i < 32; ++i) v[i] = (float)d[i >> 3].h[i & 7];

    float mx = v[0];
#pragma unroll
    for (int i = 1; i < 32; ++i) mx = fmaxf(mx, v[i]);
    mx = fmaxf(mx, __shfl_xor(mx, 4));
    mx = fmaxf(mx, __shfl_xor(mx, 8));
    mx = fmaxf(mx, __shfl_xor(mx, 16));
    mx = fmaxf(mx, __shfl_xor(mx, 32));
    __shared__ float redm[8][4], reds[8][4];
    const int wid = t >> 6, l = t & 63;
    if (l < 4) redm[wid][l] = mx;
    __syncthreads();
    mx = redm[0][t & 3];
#pragma unroll
    for (int wv2 = 1; wv2 < 8; ++wv2) mx = fmaxf(mx, redm[wv2][t & 3]);

    float s = 0.f;
#pragma unroll
    for (int i = 0; i < 32; ++i) { v[i] = __expf(v[i] - mx); s += v[i]; }
    s += __shfl_xor(s, 4);
    s += __shfl_xor(s, 8);
    s += __shfl_xor(s, 16);
    s += __shfl_xor(s, 32);
    if (l < 4) reds[wid][l] = s;
    __syncthreads();
    s = 0.f;
#pragma unroll
    for (int wv2 = 0; wv2 < 8; ++wv2) s += reds[wv2][t & 3];

    const float inv = 1.f / s;
#pragma unroll
    for (int i = 0; i < 32; ++i) d[i >> 3].h[i & 7] = (bf16)(v[i] * inv);
#pragma unroll
    for (int i = 0; i < 4; ++i) ((uint4*)rp)[i] = d[i].u;
}

extern "C" void kernel_launch(void* const* d_in, const int* in_sizes, int n_in,
                              void* d_out, int out_size, void* d_ws, size_t ws_size,
                              hipStream_t stream)
{
    (void)in_sizes; (void)n_in; (void)out_size; (void)ws_size;
    const float* T  = (const float*)d_in[0];
    const float* S  = (const float*)d_in[1];
    const float* Wq = (const float*)d_in[2];
    const float* Wk = (const float*)d_in[3];
    const float* Wv = (const float*)d_in[4];
    const float* Wo = (const float*)d_in[5];
    float* Y = (float*)d_out;
    char* ws = (char*)d_ws;

    // all bf16 arrays PANELIZED: [z][k/32][rows][32]
    bf16* Wqb = (bf16*)(ws + 0);           // 4 weights contiguous, 8MB
    bf16* Wkb = (bf16*)(ws + 2097152);
    bf16* Wvb = (bf16*)(ws + 4194304);
    bf16* Wob = (bf16*)(ws + 6291456);
    bf16* Tb  = (bf16*)(ws + 8388608);     // 16MB flat [32][8192][32]; reused as O
    bf16* Ob  = Tb;                        // O: [z][32][1024][32]
    bf16* Qb  = (bf16*)(ws + 25165824);    // 16MB [z][32][1024][32]
    bf16* Sb  = (bf16*)(ws + 41943040);    // 64MB flat [32][32768][32]; reused as P
    bf16* Pb  = Sb;                        // P: [z][128][1024][32]
    bf16* Kb  = (bf16*)(ws + 109051904);   // 64MB [z][32][4096][32]
    bf16* VTb = (bf16*)(ws + 176160768);   // 64MB [z][128 lk-panels][1024 e][32]

    // converts (panelized writes)
    cvt_w4 <<<2048,  256, 0, stream>>>(Wq, Wk, Wv, Wo, Wqb);
    cvt_pan<<<4096,  256, 0, stream>>>(T, Tb, 8192,  1048576);
    cvt_pan<<<16384, 256, 0, stream>>>(S, Sb, 32768, 4194304);

    // q = T Wq^T : C -> Qb [z][32][1024][32]
    gemm256<0><<<128, 512, 0, stream>>>(Tb, Wqb, Qb, 1024, 1024,
        0, 0, 0, 262144, 32768, 32768, 1048576, 10, 1.f, 4, 32, 4);
    // k = S Wk^T : C -> Kb [z][32][4096][32]
    gemm256<0><<<512, 512, 0, stream>>>(Sb, Wkb, Kb, 1024, 1024,
        0, 0, 0, 1048576, 32768, 131072, 4194304, 12, 1.f, 4, 128, 4);
    // v = S Wv^T -> VT directly (OMODE 1)
    gemm256<1><<<512, 512, 0, stream>>>(Sb, Wvb, VTb, 1024, 1024,
        0, 0, 0, 1048576, 32768, 0, 0, 30, 1.f, 4, 128, 4);

    // scores = (q k^T) * D^-0.5 : batched, C -> Pb [z][128][1024][32]
    gemm256<0><<<512, 512, 0, stream>>>(Qb, Kb, Pb, 1024, 4096,
        1048576, 4194304, 4194304, 32768, 131072, 32768, 0, 30,
        0.03125f, 16, 4, 4);

    softmax_pan<<<2048, 512, 0, stream>>>(Pb);

    // O = P V : batched, K=4096, C -> Ob [z][32][1024][32]
    gemm256<0><<<128, 512, 0, stream>>>(Pb, VTb, Ob, 4096, 1024,
        4194304, 4194304, 1048576, 32768, 32768, 32768, 0, 30,
        1.f, 4, 4, 4);

    // Y = O Wo^T : batched over z, f32 row-major out
    gemm256<2><<<128, 512, 0, stream>>>(Ob, Wob, Y, 1024, 1024,
        1048576, 0, 1048576, 32768, 32768, 0, 0, 30, 1.f, 4, 4, 4);
}